// Round 16
// baseline (175.567 us; speedup 1.0000x reference)
//
#include <hip/hip_runtime.h>
#include <hip/hip_bf16.h>
#include <cstdint>

#define NHEAD 16
#define ORDERS 4

typedef short short8 __attribute__((ext_vector_type(8)));
typedef float f32x4 __attribute__((ext_vector_type(4)));

__device__ __forceinline__ unsigned short f32_to_bf16_rtn(float f) {
  union { float f; unsigned u; } v; v.f = f;
  unsigned r = v.u + 0x7FFFu + ((v.u >> 16) & 1u);
  return (unsigned short)(r >> 16);
}

typedef __attribute__((address_space(1))) void gvoid;
typedef __attribute__((address_space(3))) void svoid;
__device__ __forceinline__ void gload_lds16(const void* g, void* l) {
  // LDS dest = base + lane*16 (wave-uniform base); global src is per-lane
  __builtin_amdgcn_global_load_lds((gvoid*)g, (svoid*)l, 16, 0, 0);
}

// ====== weff kernel: block (h, 64-col chunk c) computes M_h then W_eff ======
__global__ __launch_bounds__(256) void weff_kernel(
    const float* __restrict__ A, const float* __restrict__ t_ptr,
    const float* __restrict__ W, const float* __restrict__ bvec,
    unsigned short* __restrict__ Weff, float* __restrict__ beff) {
  __shared__ float Ah[64 * 65];  // reused as Mh (stride 64) after the orders
  __shared__ float T0[64 * 64];
  __shared__ float T1[64 * 64];

  const int tid = threadIdx.x;
  const int h = blockIdx.x >> 4;
  const int c = blockIdx.x & 15;
  const int d = tid & 63;
  const int ig = tid >> 6;

  float wreg[16];
  #pragma unroll
  for (int r = 0; r < 16; ++r)
    wreg[r] = W[(size_t)(h * 64 + ig * 16 + r) * 1024 + c * 64 + d];

  const float t = t_ptr[0];
  const int i = tid >> 2;
  const int jq = (tid & 3) << 4;

  for (int r = 0; r < 16; ++r) {
    int idx = tid + 256 * r;
    Ah[(idx >> 6) * 65 + (idx & 63)] = A[h * 4096 + idx];
  }
  float ms[16];
  #pragma unroll
  for (int cc = 0; cc < 16; ++cc) {
    float e = (i == jq + cc) ? 1.0f : 0.0f;
    T0[i * 64 + jq + cc] = e;
    ms[cc] = e;
  }
  __syncthreads();

  float* Tc = T0;
  float* Tn = T1;
  for (int k = 1; k <= ORDERS; ++k) {
    float scale = t / (float)k;
    float acc[16];
    #pragma unroll
    for (int cc = 0; cc < 16; ++cc) acc[cc] = 0.f;
    for (int l = 0; l < 64; ++l) {
      float a = Ah[i * 65 + l];
      float4 t0 = *(const float4*)&Tc[l * 64 + jq];
      float4 t1 = *(const float4*)&Tc[l * 64 + jq + 4];
      float4 t2 = *(const float4*)&Tc[l * 64 + jq + 8];
      float4 t3 = *(const float4*)&Tc[l * 64 + jq + 12];
      acc[0] += a * t0.x;  acc[1] += a * t0.y;  acc[2] += a * t0.z;  acc[3] += a * t0.w;
      acc[4] += a * t1.x;  acc[5] += a * t1.y;  acc[6] += a * t1.z;  acc[7] += a * t1.w;
      acc[8] += a * t2.x;  acc[9] += a * t2.y;  acc[10] += a * t2.z; acc[11] += a * t2.w;
      acc[12] += a * t3.x; acc[13] += a * t3.y; acc[14] += a * t3.z; acc[15] += a * t3.w;
    }
    #pragma unroll
    for (int cc = 0; cc < 16; ++cc) { acc[cc] *= scale; ms[cc] += acc[cc]; }
    #pragma unroll
    for (int u = 0; u < 4; ++u) {
      float4 v = {acc[u * 4], acc[u * 4 + 1], acc[u * 4 + 2], acc[u * 4 + 3]};
      *(float4*)&Tn[i * 64 + jq + u * 4] = v;
    }
    __syncthreads();
    float* tmp = Tc; Tc = Tn; Tn = tmp;
  }

  float* Mh = Ah;
  #pragma unroll
  for (int u = 0; u < 4; ++u) {
    float4 v = {ms[u * 4], ms[u * 4 + 1], ms[u * 4 + 2], ms[u * 4 + 3]};
    *(float4*)&Mh[i * 64 + jq + u * 4] = v;
  }
  float* Wc = T0;
  #pragma unroll
  for (int r = 0; r < 16; ++r) Wc[(ig * 16 + r) * 64 + d] = wreg[r];
  __syncthreads();

  #pragma unroll
  for (int ii = 0; ii < 16; ++ii) {
    int i2 = ig * 16 + ii;
    float acc = 0.f;
    #pragma unroll
    for (int j = 0; j < 64; ++j) acc += Mh[i2 * 64 + j] * Wc[j * 64 + d];
    Weff[(size_t)(h * 64 + i2) * 1024 + c * 64 + d] = f32_to_bf16_rtn(acc);
  }
  if (c == 0 && tid < 64) {
    float acc = 0.f;
    for (int j = 0; j < 64; ++j) acc += Mh[tid * 64 + j] * bvec[h * 64 + j];
    beff[h * 64 + tid] = acc;
  }
}

// ------- Convert: X f32 -> bf16 Xb. No LDS -> full occupancy, BW-bound ------
__global__ __launch_bounds__(256) void convert_x_kernel(
    const float* __restrict__ X, unsigned short* __restrict__ Xb, int n8) {
  int idx = blockIdx.x * blockDim.x + threadIdx.x;
  int stride = gridDim.x * blockDim.x;
  for (int i = idx; i < n8; i += stride) {
    float4 a = *(const float4*)(X + (size_t)i * 8);
    float4 b = *(const float4*)(X + (size_t)i * 8 + 4);
    unsigned short t[8] = {f32_to_bf16_rtn(a.x), f32_to_bf16_rtn(a.y),
                           f32_to_bf16_rtn(a.z), f32_to_bf16_rtn(a.w),
                           f32_to_bf16_rtn(b.x), f32_to_bf16_rtn(b.y),
                           f32_to_bf16_rtn(b.z), f32_to_bf16_rtn(b.w)};
    *(uint4*)(Xb + (size_t)i * 8) = *(const uint4*)t;
  }
}

// ====== GEMM 256x256: R15's 2-barrier counted-vmcnt schedule, scaled up ======
// 512 threads / 8 waves (2Mx4N), per-wave out 128x64, acc[8][4]. K-tile parity
// double buffer: buf b: A @ b*65536 (32KB), B @ b*65536+32768 (32KB) = 128KB.
// Per K-tile: stage(j+1)->other buf (8 gloads/wave, full-iter lead); vmcnt(8);
// barrier; 24 ds_reads (bfr+afr0 | afr1, lgkm(8)/(0) split); 2x32 MFMA with
// setprio; barrier. Same hazard structure as R15 (proven), 2x drain amortization.
__global__ __launch_bounds__(512, 1) void gemm256_kernel(
    const unsigned short* __restrict__ Xb, const unsigned short* __restrict__ Wf,
    const float* __restrict__ beff, float* __restrict__ Out) {
  __shared__ __align__(16) char smem[131072];

  const int wg = blockIdx.x;
  const int swz = (wg & 7) * 64 + (wg >> 3);  // 512 % 8 == 0: bijective
  const int R = (swz >> 2) * 256;
  const int C = (swz & 3) * 256;

  const int tid = threadIdx.x;
  const int lane = tid & 63;
  const int w = tid >> 6;   // 0..7
  const int wm = w >> 2;    // rows [wm*128, +128)
  const int wn = w & 3;     // cols [wn*64, +64)
  const int frow = lane & 15;
  const int fkg = lane >> 4;
  const int fx = frow & 7;

  f32x4 acc[8][4];
  #pragma unroll
  for (int mi = 0; mi < 8; ++mi)
    #pragma unroll
    for (int ni = 0; ni < 4; ++ni) acc[mi][ni] = (f32x4){0.f, 0.f, 0.f, 0.f};

  // Staging: wave w covers rows [w*32, +32) of each 256-row operand tile.
  // 4 instr/operand, instr u = rows w*32+u*8..+8. Pre-swizzled source col
  // (slot^row&7); linear LDS dest (rule #21, R4-proven involution).
  const int lr8 = lane >> 3;           // row within 8-row group (= row&7)
  const int sl = lane & 7;
  const int scol = ((sl ^ lr8) << 3);
  const unsigned short* Asrc = Xb + (size_t)(R + w * 32 + lr8) * 1024 + scol;
  const unsigned short* Bsrc = Wf + (size_t)(C + w * 32 + lr8) * 1024 + scol;

  auto stage = [&](int kt) {  // 8 gload_lds per wave
    char* base = smem + (kt & 1) * 65536;
    char* Ad = base + w * 4096;
    char* Bd = base + 32768 + w * 4096;
    const int kb = kt * 64;
    #pragma unroll
    for (int u = 0; u < 4; ++u)
      gload_lds16(Asrc + (size_t)(u * 8) * 1024 + kb, Ad + u * 1024);
    #pragma unroll
    for (int u = 0; u < 4; ++u)
      gload_lds16(Bsrc + (size_t)(u * 8) * 1024 + kb, Bd + u * 1024);
  };

  stage(0);
  for (int j = 0; j < 16; ++j) {
    if (j < 15) {
      stage(j + 1);  // 8 loads for tile j+1 go (and stay) in flight
      asm volatile("s_waitcnt vmcnt(8)" ::: "memory");  // tile j complete
    } else {
      asm volatile("s_waitcnt vmcnt(0)" ::: "memory");
    }
    __builtin_amdgcn_sched_barrier(0);
    __builtin_amdgcn_s_barrier();  // buf[j&1] valid for all waves

    const unsigned short* As = (const unsigned short*)(smem + (j & 1) * 65536);
    const unsigned short* Bs = (const unsigned short*)(smem + (j & 1) * 65536 + 32768);

    short8 bfr[4][2], afr0[4][2], afr1[4][2];
    #pragma unroll
    for (int ni = 0; ni < 4; ++ni) {
      int br = wn * 64 + ni * 16 + frow;
      #pragma unroll
      for (int kk = 0; kk < 2; ++kk) {
        int slot = (kk * 4 + fkg) ^ fx;
        bfr[ni][kk] = *(const short8*)&Bs[br * 64 + slot * 8];
      }
    }
    #pragma unroll
    for (int mi = 0; mi < 4; ++mi) {
      int ar = wm * 128 + mi * 16 + frow;
      #pragma unroll
      for (int kk = 0; kk < 2; ++kk) {
        int slot = (kk * 4 + fkg) ^ fx;
        afr0[mi][kk] = *(const short8*)&As[ar * 64 + slot * 8];
      }
    }
    __builtin_amdgcn_sched_barrier(0);  // pin: bfr+afr0 issued first
    #pragma unroll
    for (int mi = 0; mi < 4; ++mi) {
      int ar = wm * 128 + 64 + mi * 16 + frow;
      #pragma unroll
      for (int kk = 0; kk < 2; ++kk) {
        int slot = (kk * 4 + fkg) ^ fx;
        afr1[mi][kk] = *(const short8*)&As[ar * 64 + slot * 8];
      }
    }
    asm volatile("s_waitcnt lgkmcnt(8)" ::: "memory");  // bfr+afr0 done
    __builtin_amdgcn_sched_barrier(0);
    __builtin_amdgcn_s_setprio(1);
    #pragma unroll
    for (int mi = 0; mi < 4; ++mi)
      #pragma unroll
      for (int ni = 0; ni < 4; ++ni)
        #pragma unroll
        for (int kk = 0; kk < 2; ++kk)
          acc[mi][ni] = __builtin_amdgcn_mfma_f32_16x16x32_bf16(
              afr0[mi][kk], bfr[ni][kk], acc[mi][ni], 0, 0, 0);
    __builtin_amdgcn_s_setprio(0);
    asm volatile("s_waitcnt lgkmcnt(0)" ::: "memory");  // afr1 done
    __builtin_amdgcn_sched_barrier(0);
    __builtin_amdgcn_s_setprio(1);
    #pragma unroll
    for (int mi = 0; mi < 4; ++mi)
      #pragma unroll
      for (int ni = 0; ni < 4; ++ni)
        #pragma unroll
        for (int kk = 0; kk < 2; ++kk)
          acc[4 + mi][ni] = __builtin_amdgcn_mfma_f32_16x16x32_bf16(
              afr1[mi][kk], bfr[ni][kk], acc[4 + mi][ni], 0, 0, 0);
    __builtin_amdgcn_s_setprio(0);
    __builtin_amdgcn_s_barrier();  // all reads done -> next stage may overwrite
  }
  __syncthreads();

  // Epilogue (R8-proven): 4 chunks of 64 rows staged in LDS -> float4 stores
  float* Cs = (float*)smem;  // 64*260*4 = 66560 B <= 128 KB
  const int er = tid >> 3;
  const int ecg = tid & 7;
  float4 bias[8];
  #pragma unroll
  for (int u = 0; u < 8; ++u)
    bias[u] = *(const float4*)&beff[C + ecg * 32 + u * 4];
  #pragma unroll
  for (int c = 0; c < 4; ++c) {
    if (wm == (c >> 1)) {
      #pragma unroll
      for (int m = 0; m < 4; ++m)
        #pragma unroll
        for (int ni = 0; ni < 4; ++ni)
          #pragma unroll
          for (int reg = 0; reg < 4; ++reg)
            Cs[(m * 16 + fkg * 4 + reg) * 260 + wn * 64 + ni * 16 + frow] =
                acc[(c & 1) * 4 + m][ni][reg];
    }
    __syncthreads();
    #pragma unroll
    for (int u = 0; u < 8; ++u) {
      float4 v = *(const float4*)&Cs[er * 260 + ecg * 32 + u * 4];
      v.x += bias[u].x; v.y += bias[u].y; v.z += bias[u].z; v.w += bias[u].w;
      *(float4*)(Out + (size_t)(R + c * 64 + er) * 1024 + C + ecg * 32 + u * 4) = v;
    }
    __syncthreads();
  }
}

// ---------------- Fallback GEMM (reg-staged, f32 X) if ws is small -----------
#define LDSS 72
#define CSTRF 136
__global__ __launch_bounds__(256, 2) void gemm_fb(
    const float* __restrict__ X, const unsigned short* __restrict__ Weff,
    const float* __restrict__ beff, float* __restrict__ Out) {
  __shared__ __align__(16) unsigned short As0[128 * LDSS];
  __shared__ __align__(16) unsigned short As1[128 * LDSS];
  __shared__ __align__(16) unsigned short Bs0[128 * LDSS];
  __shared__ __align__(16) unsigned short Bs1[128 * LDSS];
  const int wg = blockIdx.x;
  const int swz = (wg & 7) * 256 + (wg >> 3);
  const int R = (swz >> 3) * 128;
  const int C = (swz & 7) * 128;
  const int tid = threadIdx.x;
  const int lane = tid & 63;
  const int wave = tid >> 6;
  const int wm = wave >> 1, wn = wave & 1;
  const int frow = lane & 15, fkg = lane >> 4;
  f32x4 acc[4][4];
  #pragma unroll
  for (int mi = 0; mi < 4; ++mi)
    #pragma unroll
    for (int ni = 0; ni < 4; ++ni) acc[mi][ni] = (f32x4){0.f, 0.f, 0.f, 0.f};
  const int ar = tid >> 4, akc = (tid & 15) << 2;
  const int bn_ = tid >> 3, bkc = (tid & 7) << 3;
  const float* Xbase = X + (size_t)(R + ar) * 1024 + akc;
  const unsigned short* Wbase = Weff + (size_t)(C + bn_) * 1024 + bkc;
  float4 av[8];
  uint4 bv[4];
  auto loadTile = [&](int kt) {
    const int kb = kt * 64;
    #pragma unroll
    for (int i = 0; i < 8; ++i) av[i] = *(const float4*)(Xbase + (size_t)i * 16 * 1024 + kb);
    #pragma unroll
    for (int i = 0; i < 4; ++i) bv[i] = *(const uint4*)(Wbase + (size_t)i * 32 * 1024 + kb);
  };
  auto writeTile = [&](unsigned short* Asn, unsigned short* Bsn) {
    #pragma unroll
    for (int i = 0; i < 8; ++i) {
      unsigned short tmp[4] = {f32_to_bf16_rtn(av[i].x), f32_to_bf16_rtn(av[i].y),
                               f32_to_bf16_rtn(av[i].z), f32_to_bf16_rtn(av[i].w)};
      *(uint2*)&Asn[(ar + i * 16) * LDSS + akc] = *(const uint2*)tmp;
    }
    #pragma unroll
    for (int i = 0; i < 4; ++i) *(uint4*)&Bsn[(bn_ + i * 32) * LDSS + bkc] = bv[i];
  };
  loadTile(0);
  writeTile(As0, Bs0);
  __syncthreads();
  unsigned short* Asc = As0; unsigned short* Asn = As1;
  unsigned short* Bsc = Bs0; unsigned short* Bsn = Bs1;
  for (int kt = 0; kt < 16; ++kt) {
    if (kt < 15) loadTile(kt + 1);
    short8 afr[4][2], bfr[4][2];
    #pragma unroll
    for (int mi = 0; mi < 4; ++mi)
      #pragma unroll
      for (int kk = 0; kk < 2; ++kk)
        afr[mi][kk] = *(const short8*)&Asc[(wm * 64 + mi * 16 + frow) * LDSS + kk * 32 + fkg * 8];
    #pragma unroll
    for (int ni = 0; ni < 4; ++ni)
      #pragma unroll
      for (int kk = 0; kk < 2; ++kk)
        bfr[ni][kk] = *(const short8*)&Bsc[(wn * 64 + ni * 16 + frow) * LDSS + kk * 32 + fkg * 8];
    #pragma unroll
    for (int mi = 0; mi < 4; ++mi)
      #pragma unroll
      for (int ni = 0; ni < 4; ++ni)
        #pragma unroll
        for (int kk = 0; kk < 2; ++kk)
          acc[mi][ni] = __builtin_amdgcn_mfma_f32_16x16x32_bf16(
              afr[mi][kk], bfr[ni][kk], acc[mi][ni], 0, 0, 0);
    if (kt < 15) writeTile(Asn, Bsn);
    __syncthreads();
    unsigned short* t1 = Asc; Asc = Asn; Asn = t1;
    unsigned short* t2 = Bsc; Bsc = Bsn; Bsn = t2;
  }
  float* Cs = (float*)As0;
  const int c4 = (tid & 31) << 2;
  float4 bb = *(const float4*)&beff[C + c4];
  #pragma unroll
  for (int mi = 0; mi < 4; ++mi) {
    #pragma unroll
    for (int ni = 0; ni < 4; ++ni) {
      int col = wn * 64 + ni * 16 + frow;
      #pragma unroll
      for (int reg = 0; reg < 4; ++reg)
        Cs[(wm * 16 + fkg * 4 + reg) * CSTRF + col] = acc[mi][ni][reg];
    }
    __syncthreads();
    #pragma unroll
    for (int it = 0; it < 4; ++it) {
      int rloc = it * 8 + (tid >> 5);
      float4 v = *(const float4*)&Cs[rloc * CSTRF + c4];
      v.x += bb.x; v.y += bb.y; v.z += bb.z; v.w += bb.w;
      int grow = R + (rloc >> 4) * 64 + mi * 16 + (rloc & 15);
      *(float4*)(Out + (size_t)grow * 1024 + C + c4) = v;
    }
    __syncthreads();
  }
}

extern "C" void kernel_launch(void* const* d_in, const int* in_sizes, int n_in,
                              void* d_out, int out_size, void* d_ws, size_t ws_size,
                              hipStream_t stream) {
  const float* x = (const float*)d_in[0];
  const float* t = (const float*)d_in[1];
  const float* W = (const float*)d_in[2];
  const float* b = (const float*)d_in[3];
  const float* A = (const float*)d_in[4];
  float* out = (float*)d_out;

  char* ws = (char*)d_ws;
  unsigned short* Weff = (unsigned short*)ws;                 // 2 MB @ 0
  float* beff = (float*)(ws + (2 << 20));                     // 4 KB @ 2 MB
  unsigned short* Xb = (unsigned short*)(ws + (4ull << 20));  // 64 MB @ 4 MB

  const size_t need = (4ull << 20) + (64ull << 20);
  weff_kernel<<<256, 256, 0, stream>>>(A, t, W, b, Weff, beff);
  if (ws_size >= need) {
    convert_x_kernel<<<2048, 256, 0, stream>>>(x, Xb, 33554432 / 8);
    gemm256_kernel<<<512, 512, 0, stream>>>(Xb, Weff, beff, out);
  } else {
    gemm_fb<<<2048, 256, 0, stream>>>(x, Weff, beff, out);
  }
}

// Round 17
// 153.852 us; speedup vs baseline: 1.1411x; 1.1411x over previous
//
#include <hip/hip_runtime.h>
#include <hip/hip_bf16.h>
#include <cstdint>

#define NHEAD 16
#define ORDERS 4

typedef short short8 __attribute__((ext_vector_type(8)));
typedef float f32x4 __attribute__((ext_vector_type(4)));

__device__ __forceinline__ unsigned short f32_to_bf16_rtn(float f) {
  union { float f; unsigned u; } v; v.f = f;
  unsigned r = v.u + 0x7FFFu + ((v.u >> 16) & 1u);
  return (unsigned short)(r >> 16);
}

// packed f32x2 -> bf16x2 RNE (v_cvt_pk_bf16_f32); .x lands in low 16 bits
__device__ __forceinline__ unsigned pack2(float lo, float hi) {
  __hip_bfloat162 h = __float22bfloat162_rn(float2{lo, hi});
  return *reinterpret_cast<unsigned*>(&h);
}

typedef __attribute__((address_space(1))) void gvoid;
typedef __attribute__((address_space(3))) void svoid;
__device__ __forceinline__ void gload_lds16(const void* g, void* l) {
  // LDS dest = base + lane*16 (wave-uniform base); global src is per-lane
  __builtin_amdgcn_global_load_lds((gvoid*)g, (svoid*)l, 16, 0, 0);
}

// ====== weff kernel: block (h, 64-col chunk c) computes M_h then W_eff ======
__global__ __launch_bounds__(256) void weff_kernel(
    const float* __restrict__ A, const float* __restrict__ t_ptr,
    const float* __restrict__ W, const float* __restrict__ bvec,
    unsigned short* __restrict__ Weff, float* __restrict__ beff) {
  __shared__ float Ah[64 * 65];  // reused as Mh (stride 64) after the orders
  __shared__ float T0[64 * 64];
  __shared__ float T1[64 * 64];

  const int tid = threadIdx.x;
  const int h = blockIdx.x >> 4;
  const int c = blockIdx.x & 15;
  const int d = tid & 63;
  const int ig = tid >> 6;

  float wreg[16];
  #pragma unroll
  for (int r = 0; r < 16; ++r)
    wreg[r] = W[(size_t)(h * 64 + ig * 16 + r) * 1024 + c * 64 + d];

  const float t = t_ptr[0];
  const int i = tid >> 2;
  const int jq = (tid & 3) << 4;

  for (int r = 0; r < 16; ++r) {
    int idx = tid + 256 * r;
    Ah[(idx >> 6) * 65 + (idx & 63)] = A[h * 4096 + idx];
  }
  float ms[16];
  #pragma unroll
  for (int cc = 0; cc < 16; ++cc) {
    float e = (i == jq + cc) ? 1.0f : 0.0f;
    T0[i * 64 + jq + cc] = e;
    ms[cc] = e;
  }
  __syncthreads();

  float* Tc = T0;
  float* Tn = T1;
  for (int k = 1; k <= ORDERS; ++k) {
    float scale = t / (float)k;
    float acc[16];
    #pragma unroll
    for (int cc = 0; cc < 16; ++cc) acc[cc] = 0.f;
    for (int l = 0; l < 64; ++l) {
      float a = Ah[i * 65 + l];
      float4 t0 = *(const float4*)&Tc[l * 64 + jq];
      float4 t1 = *(const float4*)&Tc[l * 64 + jq + 4];
      float4 t2 = *(const float4*)&Tc[l * 64 + jq + 8];
      float4 t3 = *(const float4*)&Tc[l * 64 + jq + 12];
      acc[0] += a * t0.x;  acc[1] += a * t0.y;  acc[2] += a * t0.z;  acc[3] += a * t0.w;
      acc[4] += a * t1.x;  acc[5] += a * t1.y;  acc[6] += a * t1.z;  acc[7] += a * t1.w;
      acc[8] += a * t2.x;  acc[9] += a * t2.y;  acc[10] += a * t2.z; acc[11] += a * t2.w;
      acc[12] += a * t3.x; acc[13] += a * t3.y; acc[14] += a * t3.z; acc[15] += a * t3.w;
    }
    #pragma unroll
    for (int cc = 0; cc < 16; ++cc) { acc[cc] *= scale; ms[cc] += acc[cc]; }
    #pragma unroll
    for (int u = 0; u < 4; ++u) {
      float4 v = {acc[u * 4], acc[u * 4 + 1], acc[u * 4 + 2], acc[u * 4 + 3]};
      *(float4*)&Tn[i * 64 + jq + u * 4] = v;
    }
    __syncthreads();
    float* tmp = Tc; Tc = Tn; Tn = tmp;
  }

  float* Mh = Ah;
  #pragma unroll
  for (int u = 0; u < 4; ++u) {
    float4 v = {ms[u * 4], ms[u * 4 + 1], ms[u * 4 + 2], ms[u * 4 + 3]};
    *(float4*)&Mh[i * 64 + jq + u * 4] = v;
  }
  float* Wc = T0;
  #pragma unroll
  for (int r = 0; r < 16; ++r) Wc[(ig * 16 + r) * 64 + d] = wreg[r];
  __syncthreads();

  #pragma unroll
  for (int ii = 0; ii < 16; ++ii) {
    int i2 = ig * 16 + ii;
    float acc = 0.f;
    #pragma unroll
    for (int j = 0; j < 64; ++j) acc += Mh[i2 * 64 + j] * Wc[j * 64 + d];
    Weff[(size_t)(h * 64 + i2) * 1024 + c * 64 + d] = f32_to_bf16_rtn(acc);
  }
  if (c == 0 && tid < 64) {
    float acc = 0.f;
    for (int j = 0; j < 64; ++j) acc += Mh[tid * 64 + j] * bvec[h * 64 + j];
    beff[h * 64 + tid] = acc;
  }
}

// ====== GEMM single-pass: out = bf16(X) @ Weff^T + beff ======================
// R15 schedule; A staged as f32 via gload_lds with DOUBLE buffer (counted
// vmcnt, full-iteration lead) + 16-slot XOR swizzle; cvt_pk at fragment-read.
// B (L2-resident Weff) SINGLE buffer, staged post-read-barrier. LDS:
// A buf0 @0, A buf1 @32768, B @65536 (16K) = 80KB -> 2 blocks/CU.
// R11/R12's failure was the B-dbuf stride bug (8192 vs 16384), not this path.
#define CSTR 132  // padded f32 stride for epilogue staging

__global__ __launch_bounds__(256, 2) void gemm_kernel(
    const float* __restrict__ X, const unsigned short* __restrict__ Wf,
    const float* __restrict__ beff, float* __restrict__ Out) {
  __shared__ __align__(16) char smem[81920];

  const int wg = blockIdx.x;
  const int swz = (wg & 7) * 256 + (wg >> 3);  // 2048 % 8 == 0: bijective
  const int R = (swz >> 3) * 128;
  const int C = (swz & 7) * 128;

  const int tid = threadIdx.x;
  const int lane = tid & 63;
  const int wave = tid >> 6;
  const int wm = wave >> 1;
  const int wn = wave & 1;
  const int frow = lane & 15;
  const int fkg = lane >> 4;

  f32x4 acc[4][4];
  #pragma unroll
  for (int mi = 0; mi < 4; ++mi)
    #pragma unroll
    for (int ni = 0; ni < 4; ++ni) acc[mi][ni] = (f32x4){0.f, 0.f, 0.f, 0.f};

  // ---- A staging: f32, 8 gload_lds/wave (4 rows x 256B each). Source col
  //      pre-swizzled by seg^(row&15); LDS dest linear row-major (rule #21).
  const int lr4 = lane >> 4;  // row within 4-row group
  const int seg = lane & 15;  // 16B slot
  auto stageA = [&](int kt, int bufSel) {
    char* Ad = smem + bufSel * 32768 + wave * 8192;
    #pragma unroll
    for (int c = 0; c < 8; ++c) {
      int rmod = (c * 4 + lr4) & 15;
      const float* src = X + (size_t)(R + wave * 32 + c * 4 + lr4) * 1024 +
                         ((seg ^ rmod) << 2) + kt * 64;
      gload_lds16(src, Ad + c * 1024);
    }
  };

  // ---- B staging (R15-proven path, SINGLE 16KB buffer @65536)
  const int lr8 = lane >> 3;
  const int lc = lane & 7;
  const unsigned short* Bsrc = Wf + (size_t)(C + wave * 32 + lr8) * 1024 + ((lc ^ lr8) << 3);
  auto stageB = [&](int kt) {  // 4 gload_lds per wave
    char* Bd = smem + 65536 + wave * 4096;
    const int kb = kt * 64;
    #pragma unroll
    for (int i = 0; i < 4; ++i)
      gload_lds16(Bsrc + (size_t)(i * 8) * 1024 + kb, Bd + i * 1024);
  };

  // Prologue: A(0) + B(0) in flight.
  stageA(0, 0);
  stageB(0);
  for (int kt = 0; kt < 16; ++kt) {
    if (kt < 15) {
      stageA(kt + 1, (kt + 1) & 1);  // 8 loads, stay in flight across barrier
      asm volatile("s_waitcnt vmcnt(8)" ::: "memory");  // A(kt)+B(kt) complete
    } else {
      asm volatile("s_waitcnt vmcnt(0)" ::: "memory");
    }
    __builtin_amdgcn_sched_barrier(0);
    __builtin_amdgcn_s_barrier();  // tile kt fully in LDS for all waves

    const char* Abuf = smem + (kt & 1) * 32768;
    const unsigned short* Bb = (const unsigned short*)(smem + 65536);

    // A fragments: f32 swizzled 16B reads -> cvt_pk to bf16
    short8 afr[4][2];
    #pragma unroll
    for (int mi = 0; mi < 4; ++mi) {
      int ar = wm * 64 + mi * 16 + frow;  // ar & 15 == frow
      #pragma unroll
      for (int kk = 0; kk < 2; ++kk) {
        int s0 = kk * 8 + fkg * 2;
        float4 lo = *(const float4*)(Abuf + ar * 256 + ((s0 ^ frow) << 4));
        float4 hi = *(const float4*)(Abuf + ar * 256 + (((s0 + 1) ^ frow) << 4));
        union { unsigned u[4]; short8 s; } cv;
        cv.u[0] = pack2(lo.x, lo.y);
        cv.u[1] = pack2(lo.z, lo.w);
        cv.u[2] = pack2(hi.x, hi.y);
        cv.u[3] = pack2(hi.z, hi.w);
        afr[mi][kk] = cv.s;
      }
    }
    // B fragments (bf16, proven path)
    short8 bfr[4][2];
    #pragma unroll
    for (int ni = 0; ni < 4; ++ni) {
      int br = wn * 64 + ni * 16 + frow;
      #pragma unroll
      for (int kk = 0; kk < 2; ++kk) {
        int slot = (kk * 4 + fkg) ^ (br & 7);
        bfr[ni][kk] = *(const short8*)&Bb[br * 64 + slot * 8];
      }
    }
    asm volatile("s_waitcnt lgkmcnt(0)" ::: "memory");  // my reads done
    __builtin_amdgcn_sched_barrier(0);
    __builtin_amdgcn_s_barrier();  // ALL waves' B reads done -> Bbuf reusable

    if (kt < 15) stageB(kt + 1);  // B(kt+1): L2-hot, covered by MFMA below

    __builtin_amdgcn_s_setprio(1);
    #pragma unroll
    for (int mi = 0; mi < 4; ++mi)
      #pragma unroll
      for (int ni = 0; ni < 4; ++ni)
        #pragma unroll
        for (int kk = 0; kk < 2; ++kk)
          acc[mi][ni] = __builtin_amdgcn_mfma_f32_16x16x32_bf16(
              afr[mi][kk], bfr[ni][kk], acc[mi][ni], 0, 0, 0);
    __builtin_amdgcn_s_setprio(0);
  }
  __syncthreads();

  // Epilogue: stage 32x128 f32 tile through LDS -> full-line float4 stores
  float* Cs = (float*)smem;  // 32*132*4 = 16896 B
  const int c4 = (tid & 31) << 2;
  float4 bb = *(const float4*)&beff[C + c4];
  #pragma unroll
  for (int mi = 0; mi < 4; ++mi) {
    #pragma unroll
    for (int ni = 0; ni < 4; ++ni) {
      int col = wn * 64 + ni * 16 + frow;
      #pragma unroll
      for (int reg = 0; reg < 4; ++reg)
        Cs[(wm * 16 + fkg * 4 + reg) * CSTR + col] = acc[mi][ni][reg];
    }
    __syncthreads();
    #pragma unroll
    for (int it = 0; it < 4; ++it) {
      int rloc = it * 8 + (tid >> 5);
      float4 v = *(const float4*)&Cs[rloc * CSTR + c4];
      v.x += bb.x; v.y += bb.y; v.z += bb.z; v.w += bb.w;
      int grow = R + (rloc >> 4) * 64 + mi * 16 + (rloc & 15);
      *(float4*)(Out + (size_t)grow * 1024 + C + c4) = v;
    }
    __syncthreads();
  }
}

extern "C" void kernel_launch(void* const* d_in, const int* in_sizes, int n_in,
                              void* d_out, int out_size, void* d_ws, size_t ws_size,
                              hipStream_t stream) {
  const float* x = (const float*)d_in[0];
  const float* t = (const float*)d_in[1];
  const float* W = (const float*)d_in[2];
  const float* b = (const float*)d_in[3];
  const float* A = (const float*)d_in[4];
  float* out = (float*)d_out;

  char* ws = (char*)d_ws;
  unsigned short* Weff = (unsigned short*)ws;  // 2 MB @ 0
  float* beff = (float*)(ws + (2 << 20));      // 4 KB @ 2 MB

  weff_kernel<<<256, 256, 0, stream>>>(A, t, W, b, Weff, beff);
  gemm_kernel<<<2048, 256, 0, stream>>>(x, Weff, beff, out);
}

// Round 18
// 139.338 us; speedup vs baseline: 1.2600x; 1.1042x over previous
//
#include <hip/hip_runtime.h>
#include <hip/hip_bf16.h>
#include <cstdint>

#define NHEAD 16
#define ORDERS 4

typedef short short8 __attribute__((ext_vector_type(8)));
typedef float f32x4 __attribute__((ext_vector_type(4)));

__device__ __forceinline__ unsigned short f32_to_bf16_rtn(float f) {
  union { float f; unsigned u; } v; v.f = f;
  unsigned r = v.u + 0x7FFFu + ((v.u >> 16) & 1u);
  return (unsigned short)(r >> 16);
}

typedef __attribute__((address_space(1))) void gvoid;
typedef __attribute__((address_space(3))) void svoid;
__device__ __forceinline__ void gload_lds16(const void* g, void* l) {
  // LDS dest = base + lane*16 (wave-uniform base); global src is per-lane
  __builtin_amdgcn_global_load_lds((gvoid*)g, (svoid*)l, 16, 0, 0);
}

// ====== weff kernel: block (h, 64-col chunk c) computes M_h then W_eff ======
__global__ __launch_bounds__(256) void weff_kernel(
    const float* __restrict__ A, const float* __restrict__ t_ptr,
    const float* __restrict__ W, const float* __restrict__ bvec,
    unsigned short* __restrict__ Weff, float* __restrict__ beff) {
  __shared__ float Ah[64 * 65];  // reused as Mh (stride 64) after the orders
  __shared__ float T0[64 * 64];
  __shared__ float T1[64 * 64];

  const int tid = threadIdx.x;
  const int h = blockIdx.x >> 4;
  const int c = blockIdx.x & 15;
  const int d = tid & 63;
  const int ig = tid >> 6;

  float wreg[16];
  #pragma unroll
  for (int r = 0; r < 16; ++r)
    wreg[r] = W[(size_t)(h * 64 + ig * 16 + r) * 1024 + c * 64 + d];

  const float t = t_ptr[0];
  const int i = tid >> 2;
  const int jq = (tid & 3) << 4;

  for (int r = 0; r < 16; ++r) {
    int idx = tid + 256 * r;
    Ah[(idx >> 6) * 65 + (idx & 63)] = A[h * 4096 + idx];
  }
  float ms[16];
  #pragma unroll
  for (int cc = 0; cc < 16; ++cc) {
    float e = (i == jq + cc) ? 1.0f : 0.0f;
    T0[i * 64 + jq + cc] = e;
    ms[cc] = e;
  }
  __syncthreads();

  float* Tc = T0;
  float* Tn = T1;
  for (int k = 1; k <= ORDERS; ++k) {
    float scale = t / (float)k;
    float acc[16];
    #pragma unroll
    for (int cc = 0; cc < 16; ++cc) acc[cc] = 0.f;
    for (int l = 0; l < 64; ++l) {
      float a = Ah[i * 65 + l];
      float4 t0 = *(const float4*)&Tc[l * 64 + jq];
      float4 t1 = *(const float4*)&Tc[l * 64 + jq + 4];
      float4 t2 = *(const float4*)&Tc[l * 64 + jq + 8];
      float4 t3 = *(const float4*)&Tc[l * 64 + jq + 12];
      acc[0] += a * t0.x;  acc[1] += a * t0.y;  acc[2] += a * t0.z;  acc[3] += a * t0.w;
      acc[4] += a * t1.x;  acc[5] += a * t1.y;  acc[6] += a * t1.z;  acc[7] += a * t1.w;
      acc[8] += a * t2.x;  acc[9] += a * t2.y;  acc[10] += a * t2.z; acc[11] += a * t2.w;
      acc[12] += a * t3.x; acc[13] += a * t3.y; acc[14] += a * t3.z; acc[15] += a * t3.w;
    }
    #pragma unroll
    for (int cc = 0; cc < 16; ++cc) { acc[cc] *= scale; ms[cc] += acc[cc]; }
    #pragma unroll
    for (int u = 0; u < 4; ++u) {
      float4 v = {acc[u * 4], acc[u * 4 + 1], acc[u * 4 + 2], acc[u * 4 + 3]};
      *(float4*)&Tn[i * 64 + jq + u * 4] = v;
    }
    __syncthreads();
    float* tmp = Tc; Tc = Tn; Tn = tmp;
  }

  float* Mh = Ah;
  #pragma unroll
  for (int u = 0; u < 4; ++u) {
    float4 v = {ms[u * 4], ms[u * 4 + 1], ms[u * 4 + 2], ms[u * 4 + 3]};
    *(float4*)&Mh[i * 64 + jq + u * 4] = v;
  }
  float* Wc = T0;
  #pragma unroll
  for (int r = 0; r < 16; ++r) Wc[(ig * 16 + r) * 64 + d] = wreg[r];
  __syncthreads();

  #pragma unroll
  for (int ii = 0; ii < 16; ++ii) {
    int i2 = ig * 16 + ii;
    float acc = 0.f;
    #pragma unroll
    for (int j = 0; j < 64; ++j) acc += Mh[i2 * 64 + j] * Wc[j * 64 + d];
    Weff[(size_t)(h * 64 + i2) * 1024 + c * 64 + d] = f32_to_bf16_rtn(acc);
  }
  if (c == 0 && tid < 64) {
    float acc = 0.f;
    for (int j = 0; j < 64; ++j) acc += Mh[tid * 64 + j] * bvec[h * 64 + j];
    beff[h * 64 + tid] = acc;
  }
}

// ------- Convert: X f32 -> bf16 Xb. No LDS -> full occupancy, BW-bound ------
__global__ __launch_bounds__(256) void convert_x_kernel(
    const float* __restrict__ X, unsigned short* __restrict__ Xb, int n8) {
  int idx = blockIdx.x * blockDim.x + threadIdx.x;
  int stride = gridDim.x * blockDim.x;
  for (int i = idx; i < n8; i += stride) {
    float4 a = *(const float4*)(X + (size_t)i * 8);
    float4 b = *(const float4*)(X + (size_t)i * 8 + 4);
    unsigned short t[8] = {f32_to_bf16_rtn(a.x), f32_to_bf16_rtn(a.y),
                           f32_to_bf16_rtn(a.z), f32_to_bf16_rtn(a.w),
                           f32_to_bf16_rtn(b.x), f32_to_bf16_rtn(b.y),
                           f32_to_bf16_rtn(b.z), f32_to_bf16_rtn(b.w)};
    *(uint4*)(Xb + (size_t)i * 8) = *(const uint4*)t;
  }
}

// ====== GEMM (R15 schedule, 48KB LDS -> 3 blocks/CU) =========================
// A: bf16 Xb, DOUBLE buffer (2x16KB @0), counted-vmcnt full-iteration lead.
// B: Weff (2MB, L2-resident), SINGLE buffer (16KB @32768), staged post-read-
// barrier (R17-verified hazard pattern); latency covered by MFMA + 3-block TLP.
// vmcnt ladder: steady vmcnt(4) = drains {A(kt),B(kt)}, keeps A(kt+1); tail 0.
#define CSTR 132  // padded f32 stride for epilogue staging

__global__ __launch_bounds__(256, 3) void gemm_kernel(
    const unsigned short* __restrict__ Xb, const unsigned short* __restrict__ Wf,
    const float* __restrict__ beff, float* __restrict__ Out) {
  __shared__ __align__(16) char smem[49152];  // A buf0 @0, A buf1 @16384, B @32768

  const int wg = blockIdx.x;
  const int swz = (wg & 7) * 256 + (wg >> 3);  // 2048 % 8 == 0: bijective
  const int R = (swz >> 3) * 128;
  const int C = (swz & 7) * 128;

  const int tid = threadIdx.x;
  const int lane = tid & 63;
  const int wave = tid >> 6;
  const int wm = wave >> 1;
  const int wn = wave & 1;
  const int frow = lane & 15;
  const int fkg = lane >> 4;

  f32x4 acc[4][4];
  #pragma unroll
  for (int mi = 0; mi < 4; ++mi)
    #pragma unroll
    for (int ni = 0; ni < 4; ++ni) acc[mi][ni] = (f32x4){0.f, 0.f, 0.f, 0.f};

  // Staging lane geometry (R4/R15-proven): pre-swizzled source col, linear dest
  const int lr8 = lane >> 3;           // row within 8-row group (= row&7)
  const int lc = lane & 7;             // dest 16B slot
  const int scol = ((lc ^ lr8) << 3);  // swizzled source col (rule #21)
  const unsigned short* Asrc = Xb + (size_t)(R + wave * 32 + lr8) * 1024 + scol;
  const unsigned short* Bsrc = Wf + (size_t)(C + wave * 32 + lr8) * 1024 + scol;

  auto stageA = [&](int kt, int bufSel) {  // 4 gload_lds per wave
    char* Ad = smem + bufSel * 16384 + wave * 4096;
    const int kb = kt * 64;
    #pragma unroll
    for (int i = 0; i < 4; ++i)
      gload_lds16(Asrc + (size_t)(i * 8) * 1024 + kb, Ad + i * 1024);
  };
  auto stageB = [&](int kt) {  // 4 gload_lds per wave, single buffer
    char* Bd = smem + 32768 + wave * 4096;
    const int kb = kt * 64;
    #pragma unroll
    for (int i = 0; i < 4; ++i)
      gload_lds16(Bsrc + (size_t)(i * 8) * 1024 + kb, Bd + i * 1024);
  };

  // Prologue: A(0) + B(0) in flight (8 loads).
  stageA(0, 0);
  stageB(0);
  for (int kt = 0; kt < 16; ++kt) {
    if (kt < 15) {
      stageA(kt + 1, (kt + 1) & 1);  // 4 loads, stay in flight across barrier
      asm volatile("s_waitcnt vmcnt(4)" ::: "memory");  // A(kt)+B(kt) complete
    } else {
      asm volatile("s_waitcnt vmcnt(0)" ::: "memory");  // A(15)+B(15)
    }
    __builtin_amdgcn_sched_barrier(0);
    __builtin_amdgcn_s_barrier();  // tile kt fully in LDS for all waves

    const unsigned short* As = (const unsigned short*)(smem + (kt & 1) * 16384);
    const unsigned short* Bb = (const unsigned short*)(smem + 32768);
    short8 afr[4][2], bfr[4][2];
    #pragma unroll
    for (int mi = 0; mi < 4; ++mi) {
      int ar = wm * 64 + mi * 16 + frow;
      #pragma unroll
      for (int kk = 0; kk < 2; ++kk) {
        int slot = (kk * 4 + fkg) ^ (ar & 7);
        afr[mi][kk] = *(const short8*)&As[ar * 64 + slot * 8];
      }
    }
    #pragma unroll
    for (int ni = 0; ni < 4; ++ni) {
      int br = wn * 64 + ni * 16 + frow;
      #pragma unroll
      for (int kk = 0; kk < 2; ++kk) {
        int slot = (kk * 4 + fkg) ^ (br & 7);
        bfr[ni][kk] = *(const short8*)&Bb[br * 64 + slot * 8];
      }
    }
    asm volatile("s_waitcnt lgkmcnt(0)" ::: "memory");  // my reads done
    __builtin_amdgcn_sched_barrier(0);
    __builtin_amdgcn_s_barrier();  // ALL waves' reads done -> B buf reusable

    if (kt < 15) stageB(kt + 1);  // L2-hot; covered by MFMA below + TLP

    __builtin_amdgcn_s_setprio(1);
    #pragma unroll
    for (int mi = 0; mi < 4; ++mi)
      #pragma unroll
      for (int ni = 0; ni < 4; ++ni)
        #pragma unroll
        for (int kk = 0; kk < 2; ++kk)
          acc[mi][ni] = __builtin_amdgcn_mfma_f32_16x16x32_bf16(
              afr[mi][kk], bfr[ni][kk], acc[mi][ni], 0, 0, 0);
    __builtin_amdgcn_s_setprio(0);
  }
  __syncthreads();

  // Epilogue: stage 32x128 f32 tile through LDS -> full-line float4 stores
  float* Cs = (float*)smem;  // 32*132*4 = 16896 B <= 48 KB
  const int c4 = (tid & 31) << 2;
  float4 bb = *(const float4*)&beff[C + c4];
  #pragma unroll
  for (int mi = 0; mi < 4; ++mi) {
    #pragma unroll
    for (int ni = 0; ni < 4; ++ni) {
      int col = wn * 64 + ni * 16 + frow;
      #pragma unroll
      for (int reg = 0; reg < 4; ++reg)
        Cs[(wm * 16 + fkg * 4 + reg) * CSTR + col] = acc[mi][ni][reg];
    }
    __syncthreads();
    #pragma unroll
    for (int it = 0; it < 4; ++it) {
      int rloc = it * 8 + (tid >> 5);
      float4 v = *(const float4*)&Cs[rloc * CSTR + c4];
      v.x += bb.x; v.y += bb.y; v.z += bb.z; v.w += bb.w;
      int grow = R + (rloc >> 4) * 64 + mi * 16 + (rloc & 15);
      *(float4*)(Out + (size_t)grow * 1024 + C + c4) = v;
    }
    __syncthreads();
  }
}

// ---------------- Fallback GEMM (reg-staged, f32 X) if ws is small -----------
#define LDSS 72
#define CSTRF 136
__global__ __launch_bounds__(256, 2) void gemm_fb(
    const float* __restrict__ X, const unsigned short* __restrict__ Weff,
    const float* __restrict__ beff, float* __restrict__ Out) {
  __shared__ __align__(16) unsigned short As0[128 * LDSS];
  __shared__ __align__(16) unsigned short As1[128 * LDSS];
  __shared__ __align__(16) unsigned short Bs0[128 * LDSS];
  __shared__ __align__(16) unsigned short Bs1[128 * LDSS];
  const int wg = blockIdx.x;
  const int swz = (wg & 7) * 256 + (wg >> 3);
  const int R = (swz >> 3) * 128;
  const int C = (swz & 7) * 128;
  const int tid = threadIdx.x;
  const int lane = tid & 63;
  const int wave = tid >> 6;
  const int wm = wave >> 1, wn = wave & 1;
  const int frow = lane & 15, fkg = lane >> 4;
  f32x4 acc[4][4];
  #pragma unroll
  for (int mi = 0; mi < 4; ++mi)
    #pragma unroll
    for (int ni = 0; ni < 4; ++ni) acc[mi][ni] = (f32x4){0.f, 0.f, 0.f, 0.f};
  const int ar = tid >> 4, akc = (tid & 15) << 2;
  const int bn_ = tid >> 3, bkc = (tid & 7) << 3;
  const float* Xbase = X + (size_t)(R + ar) * 1024 + akc;
  const unsigned short* Wbase = Weff + (size_t)(C + bn_) * 1024 + bkc;
  float4 av[8];
  uint4 bv[4];
  auto loadTile = [&](int kt) {
    const int kb = kt * 64;
    #pragma unroll
    for (int i = 0; i < 8; ++i) av[i] = *(const float4*)(Xbase + (size_t)i * 16 * 1024 + kb);
    #pragma unroll
    for (int i = 0; i < 4; ++i) bv[i] = *(const uint4*)(Wbase + (size_t)i * 32 * 1024 + kb);
  };
  auto writeTile = [&](unsigned short* Asn, unsigned short* Bsn) {
    #pragma unroll
    for (int i = 0; i < 8; ++i) {
      unsigned short tmp[4] = {f32_to_bf16_rtn(av[i].x), f32_to_bf16_rtn(av[i].y),
                               f32_to_bf16_rtn(av[i].z), f32_to_bf16_rtn(av[i].w)};
      *(uint2*)&Asn[(ar + i * 16) * LDSS + akc] = *(const uint2*)tmp;
    }
    #pragma unroll
    for (int i = 0; i < 4; ++i) *(uint4*)&Bsn[(bn_ + i * 32) * LDSS + bkc] = bv[i];
  };
  loadTile(0);
  writeTile(As0, Bs0);
  __syncthreads();
  unsigned short* Asc = As0; unsigned short* Asn = As1;
  unsigned short* Bsc = Bs0; unsigned short* Bsn = Bs1;
  for (int kt = 0; kt < 16; ++kt) {
    if (kt < 15) loadTile(kt + 1);
    short8 afr[4][2], bfr[4][2];
    #pragma unroll
    for (int mi = 0; mi < 4; ++mi)
      #pragma unroll
      for (int kk = 0; kk < 2; ++kk)
        afr[mi][kk] = *(const short8*)&Asc[(wm * 64 + mi * 16 + frow) * LDSS + kk * 32 + fkg * 8];
    #pragma unroll
    for (int ni = 0; ni < 4; ++ni)
      #pragma unroll
      for (int kk = 0; kk < 2; ++kk)
        bfr[ni][kk] = *(const short8*)&Bsc[(wn * 64 + ni * 16 + frow) * LDSS + kk * 32 + fkg * 8];
    #pragma unroll
    for (int mi = 0; mi < 4; ++mi)
      #pragma unroll
      for (int ni = 0; ni < 4; ++ni)
        #pragma unroll
        for (int kk = 0; kk < 2; ++kk)
          acc[mi][ni] = __builtin_amdgcn_mfma_f32_16x16x32_bf16(
              afr[mi][kk], bfr[ni][kk], acc[mi][ni], 0, 0, 0);
    if (kt < 15) writeTile(Asn, Bsn);
    __syncthreads();
    unsigned short* t1 = Asc; Asc = Asn; Asn = t1;
    unsigned short* t2 = Bsc; Bsc = Bsn; Bsn = t2;
  }
  float* Cs = (float*)As0;
  const int c4 = (tid & 31) << 2;
  float4 bb = *(const float4*)&beff[C + c4];
  #pragma unroll
  for (int mi = 0; mi < 4; ++mi) {
    #pragma unroll
    for (int ni = 0; ni < 4; ++ni) {
      int col = wn * 64 + ni * 16 + frow;
      #pragma unroll
      for (int reg = 0; reg < 4; ++reg)
        Cs[(wm * 16 + fkg * 4 + reg) * CSTRF + col] = acc[mi][ni][reg];
    }
    __syncthreads();
    #pragma unroll
    for (int it = 0; it < 4; ++it) {
      int rloc = it * 8 + (tid >> 5);
      float4 v = *(const float4*)&Cs[rloc * CSTRF + c4];
      v.x += bb.x; v.y += bb.y; v.z += bb.z; v.w += bb.w;
      int grow = R + (rloc >> 4) * 64 + mi * 16 + (rloc & 15);
      *(float4*)(Out + (size_t)grow * 1024 + C + c4) = v;
    }
    __syncthreads();
  }
}

extern "C" void kernel_launch(void* const* d_in, const int* in_sizes, int n_in,
                              void* d_out, int out_size, void* d_ws, size_t ws_size,
                              hipStream_t stream) {
  const float* x = (const float*)d_in[0];
  const float* t = (const float*)d_in[1];
  const float* W = (const float*)d_in[2];
  const float* b = (const float*)d_in[3];
  const float* A = (const float*)d_in[4];
  float* out = (float*)d_out;

  char* ws = (char*)d_ws;
  unsigned short* Weff = (unsigned short*)ws;                 // 2 MB @ 0
  float* beff = (float*)(ws + (2 << 20));                     // 4 KB @ 2 MB
  unsigned short* Xb = (unsigned short*)(ws + (4ull << 20));  // 64 MB @ 4 MB

  const size_t need = (4ull << 20) + (64ull << 20);
  weff_kernel<<<256, 256, 0, stream>>>(A, t, W, b, Weff, beff);
  if (ws_size >= need) {
    convert_x_kernel<<<2048, 256, 0, stream>>>(x, Xb, 33554432 / 8);
    gemm_kernel<<<2048, 256, 0, stream>>>(Xb, Weff, beff, out);
  } else {
    gemm_fb<<<2048, 256, 0, stream>>>(x, Weff, beff, out);
  }
}